// Round 1
// baseline (478.451 us; speedup 1.0000x reference)
//
#include <hip/hip_runtime.h>
#include <hip/hip_bf16.h>
#include <stdint.h>

typedef unsigned short u16;

#define Bdim 4
#define Adim 512
#define Ndim 128
#define Fdim 256
#define BA (Bdim*Adim)

#define HS 264      // Hs row stride (bf16), 528 B = 33*16 -> 16B aligned, banks +4 mod 32
#define XS 256      // XJ row stride
#define BK 32
#define BTS 40      // 80 B = 5*16 -> 16B aligned rows

typedef __attribute__((ext_vector_type(8))) __bf16 bf16x8;
typedef __attribute__((ext_vector_type(4))) float f32x4;

__device__ __forceinline__ float bf2f(u16 u){
  uint32_t v = ((uint32_t)u) << 16;
  return __builtin_bit_cast(float, v);
}
__device__ __forceinline__ u16 f2bf(float f){
  uint32_t v = __builtin_bit_cast(uint32_t, f);
  v += 0x7fffu + ((v >> 16) & 1u);     // RNE
  return (u16)(v >> 16);
}
// softplus(v) - log(2), stable both tails
__device__ __forceinline__ float ssp_f(float v){
  float m = fmaxf(v, 0.f);
  float e = __expf(-fabsf(v));
  return m + __logf(1.f + e) - 0.69314718f;
}

// ---------------- prep: transpose fp32 256x256 -> bf16 [n][k] ----------------
__global__ __launch_bounds__(256) void prep_kernel(
    const float* __restrict__ s0, u16* __restrict__ d0,
    const float* __restrict__ s1, u16* __restrict__ d1)
{
  __shared__ float tile[32][33];
  const float* src = blockIdx.y ? s1 : s0;
  u16* dst = blockIdx.y ? d1 : d0;
  int bx = (blockIdx.x & 7) * 32, by = (int)(blockIdx.x >> 3) * 32;
  int tx = threadIdx.x & 31, ty = threadIdx.x >> 5;
  #pragma unroll
  for (int r = 0; r < 4; r++)
    tile[ty + r*8][tx] = src[(size_t)(by + ty + r*8)*Fdim + bx + tx];
  __syncthreads();
  #pragma unroll
  for (int r = 0; r < 4; r++)
    dst[(size_t)(bx + ty + r*8)*Fdim + by + tx] = f2bf(tile[tx][ty + r*8]);
}

// ---------------- facts = x @ in2f_w + b  (bf16 out) ----------------
__global__ __launch_bounds__(256, 4) void facts_kernel(
    const float* __restrict__ x, const float* __restrict__ w,
    const float* __restrict__ bias, u16* __restrict__ facts)
{
  __shared__ float xs[Fdim];
  const int t = threadIdx.x;
  const int row = blockIdx.x;
  xs[t] = x[(size_t)row*Fdim + t];
  __syncthreads();
  float a0=0.f, a1=0.f, a2=0.f, a3=0.f;
  #pragma unroll 8
  for (int k = 0; k < Fdim; k += 4){
    a0 = fmaf(xs[k  ], w[(size_t)(k  )*Fdim + t], a0);
    a1 = fmaf(xs[k+1], w[(size_t)(k+1)*Fdim + t], a1);
    a2 = fmaf(xs[k+2], w[(size_t)(k+2)*Fdim + t], a2);
    a3 = fmaf(xs[k+3], w[(size_t)(k+3)*Fdim + t], a3);
  }
  facts[(size_t)row*Fdim + t] = f2bf(bias[t] + ((a0+a1)+(a2+a3)));
}

// ---------------- fused: W=ssp(r*fw1+fb1)@fw2+fb2 ; y=xi*W*xj ; out=ssp(y@f2out+b) ----
__global__ __launch_bounds__(512, 2) void fused_kernel(
    const float* __restrict__ r_ij, const u16* __restrict__ facts,
    const u16* __restrict__ fw2T, const u16* __restrict__ f2outT,
    const float* __restrict__ fw1, const float* __restrict__ fb1,
    const float* __restrict__ fb2, const float* __restrict__ f2out_b,
    const int* __restrict__ neighbors, float* __restrict__ out)
{
  __shared__ __align__(16) u16 Hs[Ndim*HS];      // 67584 B (H, then Y)
  __shared__ __align__(16) u16 XJ[Ndim*XS];      // 65536 B
  __shared__ __align__(16) u16 BTs[Fdim*BTS];    // 20480 B (weight tile [n][k])
  __shared__ int   nb_s[Ndim];
  __shared__ float r_s[Ndim];
  __shared__ u16   xi_s[Fdim];
  __shared__ float fw1_s[Fdim], fb1_s[Fdim], fb2_s[Fdim], ob_s[Fdim];

  const int tid = threadIdx.x;
  const int wg  = blockIdx.x;        // b*Adim + a
  const int b   = wg / Adim;

  if (tid < Ndim){
    nb_s[tid] = neighbors[(size_t)wg*Ndim + tid];
    r_s[tid]  = r_ij[(size_t)wg*Ndim + tid];
  }
  if (tid < Fdim){
    xi_s[tid]  = facts[(size_t)wg*Fdim + tid];
    fw1_s[tid] = fw1[tid];
    fb1_s[tid] = fb1[tid];
  } else {
    int t2 = tid - Fdim;
    fb2_s[t2] = fb2[t2];
    ob_s[t2]  = f2out_b[t2];
  }
  __syncthreads();

  // XJ gather: 128 rows * 32 chunks of 8 bf16 (16 B)
  #pragma unroll
  for (int i = 0; i < 8; i++){
    int id  = i*512 + tid;
    int row = id >> 5, ch = id & 31;
    const float4* src = (const float4*)(facts + ((size_t)(b*Adim + nb_s[row]))*Fdim + ch*8);
    *(float4*)(XJ + row*XS + ch*8) = *src;
  }
  // H[row][f] = ssp(r[row]*fw1[f] + fb1[f])
  #pragma unroll 4
  for (int i = 0; i < 64; i++){
    int id  = i*512 + tid;
    int row = id >> 8, f = id & 255;
    Hs[row*HS + f] = f2bf(ssp_f(fmaf(r_s[row], fw1_s[f], fb1_s[f])));
  }

  const int lane = tid & 63;
  const int wid  = tid >> 6;
  const int wrow = (wid >> 2) * 64;   // 0 / 64
  const int wcol = (wid & 3)  * 64;   // 0..192
  const int l16  = lane & 15;
  const int quad = lane >> 4;

  // weight-tile staging addresses (thread t -> n = t>>1, k-half = (t&1)*16)
  const int btn = tid >> 1;
  const int bth = (tid & 1) * 16;
  u16* btdst = BTs + btn*BTS + bth;
  const u16* w1src = fw2T   + (size_t)btn*Fdim + bth;
  const u16* w2src = f2outT + (size_t)btn*Fdim + bth;

  float4 pf0 = *(const float4*)(w1src);
  float4 pf1 = *(const float4*)(w1src + 8);

  f32x4 acc[4][4];
  #pragma unroll
  for (int mt = 0; mt < 4; mt++)
    #pragma unroll
    for (int ct = 0; ct < 4; ct++)
      acc[mt][ct] = (f32x4){0.f,0.f,0.f,0.f};

  // ---- GEMM1: W = H @ fw2 ----
  for (int kk = 0; kk < 8; kk++){
    __syncthreads();                      // prev BT reads done / Hs ready
    *(float4*)(btdst)     = pf0;
    *(float4*)(btdst + 8) = pf1;
    if (kk < 7){
      pf0 = *(const float4*)(w1src + (kk+1)*BK);
      pf1 = *(const float4*)(w1src + (kk+1)*BK + 8);
    } else {
      pf0 = *(const float4*)(w2src);      // prefetch GEMM2 chunk 0
      pf1 = *(const float4*)(w2src + 8);
    }
    __syncthreads();                      // BT ready
    bf16x8 af[4], bfr[4];
    #pragma unroll
    for (int mt = 0; mt < 4; mt++)
      af[mt] = *(const bf16x8*)(Hs + (wrow + mt*16 + l16)*HS + kk*BK + quad*8);
    #pragma unroll
    for (int ct = 0; ct < 4; ct++)
      bfr[ct] = *(const bf16x8*)(BTs + (wcol + ct*16 + l16)*BTS + quad*8);
    #pragma unroll
    for (int mt = 0; mt < 4; mt++)
      #pragma unroll
      for (int ct = 0; ct < 4; ct++)
        acc[mt][ct] = __builtin_amdgcn_mfma_f32_16x16x32_bf16(af[mt], bfr[ct], acc[mt][ct], 0, 0, 0);
  }

  // ---- elementwise: Y = xi * (W + fb2) * xj, write bf16 into Hs ----
  __syncthreads();                        // all Hs reads done before overwrite
  #pragma unroll
  for (int ct = 0; ct < 4; ct++){
    int f = wcol + ct*16 + l16;
    float xif  = bf2f(xi_s[f]);
    float fb2v = fb2_s[f];
    #pragma unroll
    for (int mt = 0; mt < 4; mt++){
      #pragma unroll
      for (int i = 0; i < 4; i++){
        int m = wrow + mt*16 + quad*4 + i;   // C/D layout: col=lane&15, row=quad*4+reg
        float wv = acc[mt][ct][i] + fb2v;
        float y  = xif * wv * bf2f(XJ[m*XS + f]);
        Hs[m*HS + f] = f2bf(y);
        acc[mt][ct][i] = 0.f;
      }
    }
  }
  __syncthreads();

  // ---- GEMM2: Z = Y @ f2out_w ----
  for (int kk = 0; kk < 8; kk++){
    __syncthreads();
    *(float4*)(btdst)     = pf0;
    *(float4*)(btdst + 8) = pf1;
    if (kk < 7){
      pf0 = *(const float4*)(w2src + (kk+1)*BK);
      pf1 = *(const float4*)(w2src + (kk+1)*BK + 8);
    }
    __syncthreads();
    bf16x8 af[4], bfr[4];
    #pragma unroll
    for (int mt = 0; mt < 4; mt++)
      af[mt] = *(const bf16x8*)(Hs + (wrow + mt*16 + l16)*HS + kk*BK + quad*8);
    #pragma unroll
    for (int ct = 0; ct < 4; ct++)
      bfr[ct] = *(const bf16x8*)(BTs + (wcol + ct*16 + l16)*BTS + quad*8);
    #pragma unroll
    for (int mt = 0; mt < 4; mt++)
      #pragma unroll
      for (int ct = 0; ct < 4; ct++)
        acc[mt][ct] = __builtin_amdgcn_mfma_f32_16x16x32_bf16(af[mt], bfr[ct], acc[mt][ct], 0, 0, 0);
  }

  // ---- epilogue: out = ssp(Z + f2out_b) ----
  size_t obase = (size_t)wg * (Ndim*Fdim);
  #pragma unroll
  for (int ct = 0; ct < 4; ct++){
    int f = wcol + ct*16 + l16;
    float obv = ob_s[f];
    #pragma unroll
    for (int mt = 0; mt < 4; mt++){
      #pragma unroll
      for (int i = 0; i < 4; i++){
        int m = wrow + mt*16 + quad*4 + i;
        out[obase + (size_t)m*Fdim + f] = ssp_f(acc[mt][ct][i] + obv);
      }
    }
  }
}

extern "C" void kernel_launch(void* const* d_in, const int* in_sizes, int n_in,
                              void* d_out, int out_size, void* d_ws, size_t ws_size,
                              hipStream_t stream)
{
  const float* x        = (const float*)d_in[0];
  const float* r_ij     = (const float*)d_in[1];
  // d_in[2] pairwise_mask: unused by the reference
  const float* in2f_w   = (const float*)d_in[3];
  const float* in2f_b   = (const float*)d_in[4];
  const float* f2out_w  = (const float*)d_in[5];
  const float* f2out_b  = (const float*)d_in[6];
  const float* fw1      = (const float*)d_in[7];
  const float* fb1      = (const float*)d_in[8];
  const float* fw2      = (const float*)d_in[9];
  const float* fb2      = (const float*)d_in[10];
  const int*   neighbors= (const int*)d_in[11];
  float* out = (float*)d_out;

  u16* facts  = (u16*)d_ws;                                   // BA*256 bf16 = 1 MiB
  u16* fw2T   = (u16*)((char*)d_ws + (1u<<20));               // 128 KiB
  u16* f2outT = (u16*)((char*)d_ws + (1u<<20) + (1u<<17));    // 128 KiB

  prep_kernel<<<dim3(64, 2), 256, 0, stream>>>(fw2, fw2T, f2out_w, f2outT);
  facts_kernel<<<BA, 256, 0, stream>>>(x, in2f_w, in2f_b, facts);
  fused_kernel<<<BA, 512, 0, stream>>>(r_ij, facts, fw2T, f2outT,
                                       fw1, fb1, fb2, f2out_b, neighbors, out);
}